// Round 3
// baseline (1332.651 us; speedup 1.0000x reference)
//
#include <hip/hip_runtime.h>
#include <hip/hip_bf16.h>
#include <stdint.h>

#define NEG_SLOPE 0.2f
#define EPSV 1e-16f

static __device__ __forceinline__ float b2f(unsigned short u) {
    union { float f; uint32_t i; } v; v.i = ((uint32_t)u) << 16; return v.f;
}
static __device__ __forceinline__ unsigned short f2b(float f) {
    union { float f; uint32_t i; } v; v.f = f;
    uint32_t x = v.i;
    return (unsigned short)((x + 0x7FFFu + ((x >> 16) & 1u)) >> 16);
}

// ---------------------------------------------------------------------------
// Layer-1 GEMM: h1 = x @ W1^T  (x:[N,128] f32, W1:[256,128] f32 -> h1:[N,256] bf16)
// fused with attention dots a_src1/a_dst1 [N,4] (f32, from f32 accumulators).
// Block = 256 threads, 4 nodes per block. Wave w == head w -> wave reduce.
// ---------------------------------------------------------------------------
__global__ __launch_bounds__(256) void gemm1_kernel(
    const float* __restrict__ x,
    const float* __restrict__ W1,
    const float* __restrict__ att_src1,
    const float* __restrict__ att_dst1,
    unsigned short* __restrict__ h1,
    float* __restrict__ a_src1,
    float* __restrict__ a_dst1)
{
    __shared__ float xs[4][128];
    const int node0 = blockIdx.x * 4;
    const int t = threadIdx.x;

    // stage 4 x-rows (512 f32) into LDS: each thread loads one float2
    const float2* xr = (const float2*)(x + (size_t)node0 * 128);
    float2 u = xr[t];
    int fl = t * 2;
    xs[fl >> 7][fl & 127]       = u.x;
    xs[fl >> 7][(fl & 127) + 1] = u.y;
    __syncthreads();

    const float4* wv = (const float4*)(W1 + (size_t)t * 128);
    float acc0 = 0.f, acc1 = 0.f, acc2 = 0.f, acc3 = 0.f;
    #pragma unroll 8
    for (int k4 = 0; k4 < 32; ++k4) {
        float4 w = wv[k4];
        int k0 = k4 * 4;
        float wf[4] = {w.x, w.y, w.z, w.w};
        #pragma unroll
        for (int i = 0; i < 4; ++i) {
            float wfi = wf[i];
            acc0 += xs[0][k0 + i] * wfi;
            acc1 += xs[1][k0 + i] * wfi;
            acc2 += xs[2][k0 + i] * wfi;
            acc3 += xs[3][k0 + i] * wfi;
        }
    }

    size_t base = (size_t)node0 * 256 + t;
    h1[base]       = f2b(acc0);
    h1[base + 256] = f2b(acc1);
    h1[base + 512] = f2b(acc2);
    h1[base + 768] = f2b(acc3);

    const float asw = att_src1[t];
    const float adw = att_dst1[t];
    const int lane = t & 63, head = t >> 6;
    float accs[4] = {acc0, acc1, acc2, acc3};
    #pragma unroll
    for (int j = 0; j < 4; ++j) {
        float ps = accs[j] * asw;
        float pd = accs[j] * adw;
        #pragma unroll
        for (int off = 32; off; off >>= 1) {
            ps += __shfl_xor(ps, off);
            pd += __shfl_xor(pd, off);
        }
        if (lane == 0) {
            a_src1[(size_t)(node0 + j) * 4 + head] = ps;
            a_dst1[(size_t)(node0 + j) * 4 + head] = pd;
        }
    }
}

// edges 0..E-1 from edge_index, edges E..ET-1 are self loops
static __device__ __forceinline__ void edge_sd(const int* __restrict__ ei,
                                               int e, int E, int& s, int& d) {
    if (e < E) { s = ei[e]; d = ei[E + e]; }
    else       { s = e - E; d = s; }
}

static __device__ __forceinline__ float edge_exp(float as, float ad) {
    float a = as + ad;
    a = a > 0.f ? a : NEG_SLOPE * a;
    return __expf(a);   // no max-subtraction: softmax shift-invariant, |a| is O(10)
}

__global__ void edge_alpha1_kernel(
    const int* __restrict__ ei, int E, int ET,
    const float4* __restrict__ a_src1, const float4* __restrict__ a_dst1,
    float* __restrict__ denom1)
{
    int e = blockIdx.x * blockDim.x + threadIdx.x;
    if (e >= ET) return;
    int s, d; edge_sd(ei, e, E, s, d);
    float4 as = a_src1[s];
    float4 ad = a_dst1[d];
    atomicAdd(&denom1[(size_t)d * 4 + 0], edge_exp(as.x, ad.x));
    atomicAdd(&denom1[(size_t)d * 4 + 1], edge_exp(as.y, ad.y));
    atomicAdd(&denom1[(size_t)d * 4 + 2], edge_exp(as.z, ad.z));
    atomicAdd(&denom1[(size_t)d * 4 + 3], edge_exp(as.w, ad.w));
}

__global__ __launch_bounds__(256) void aggregate1_kernel(
    const int* __restrict__ ei, int E,
    const unsigned short* __restrict__ h1,
    const float* __restrict__ a_src1, const float* __restrict__ a_dst1,
    const float* __restrict__ denom1, float* __restrict__ out1)
{
    int e = blockIdx.x;
    int s, d; edge_sd(ei, e, E, s, d);
    int t = threadIdx.x;
    int h = t >> 6;
    float ex = edge_exp(a_src1[(size_t)s * 4 + h], a_dst1[(size_t)d * 4 + h]);
    float coef = ex / (denom1[(size_t)d * 4 + h] + EPSV);
    float v = b2f(h1[(size_t)s * 256 + t]) * coef;
    atomicAdd(&out1[(size_t)d * 256 + t], v);
}

// Layer-2: h2[n,:2] = relu(out1[n,:]+b1) @ W2^T, plus attention dots
__global__ __launch_bounds__(256) void layer2_kernel(
    const float* __restrict__ out1, const float* __restrict__ b1,
    const float* __restrict__ W2,
    const float* __restrict__ as2, const float* __restrict__ ad2,
    float* __restrict__ h2, float* __restrict__ a_src2, float* __restrict__ a_dst2)
{
    int n = blockIdx.x, t = threadIdx.x;
    float v = out1[(size_t)n * 256 + t] + b1[t];
    v = v > 0.f ? v : 0.f;
    float p0 = v * W2[t];
    float p1 = v * W2[256 + t];
    #pragma unroll
    for (int off = 32; off; off >>= 1) {
        p0 += __shfl_xor(p0, off);
        p1 += __shfl_xor(p1, off);
    }
    __shared__ float s0[4], s1[4];
    int lane = t & 63, w = t >> 6;
    if (lane == 0) { s0[w] = p0; s1[w] = p1; }
    __syncthreads();
    if (t == 0) {
        float h0  = s0[0] + s0[1] + s0[2] + s0[3];
        float h1v = s1[0] + s1[1] + s1[2] + s1[3];
        h2[(size_t)n * 2]     = h0;
        h2[(size_t)n * 2 + 1] = h1v;
        a_src2[n] = h0 * as2[0] + h1v * as2[1];
        a_dst2[n] = h0 * ad2[0] + h1v * ad2[1];
    }
}

__global__ void edge_alpha2_kernel(
    const int* __restrict__ ei, int E, int ET,
    const float* __restrict__ a_src2, const float* __restrict__ a_dst2,
    float* __restrict__ denom2)
{
    int e = blockIdx.x * blockDim.x + threadIdx.x;
    if (e >= ET) return;
    int s, d; edge_sd(ei, e, E, s, d);
    atomicAdd(&denom2[d], edge_exp(a_src2[s], a_dst2[d]));
}

__global__ void aggregate2_kernel(
    const int* __restrict__ ei, int E, int ET,
    const float* __restrict__ h2,
    const float* __restrict__ a_src2, const float* __restrict__ a_dst2,
    const float* __restrict__ denom2, float* __restrict__ out2)
{
    int e = blockIdx.x * blockDim.x + threadIdx.x;
    if (e >= ET) return;
    int s, d; edge_sd(ei, e, E, s, d);
    float ex = edge_exp(a_src2[s], a_dst2[d]);
    float coef = ex / (denom2[d] + EPSV);
    atomicAdd(&out2[(size_t)d * 2],     h2[(size_t)s * 2]     * coef);
    atomicAdd(&out2[(size_t)d * 2 + 1], h2[(size_t)s * 2 + 1] * coef);
}

__global__ void finalize_kernel(
    const float* __restrict__ out2, const float* __restrict__ b2,
    float* __restrict__ out, int n2)
{
    int i = blockIdx.x * blockDim.x + threadIdx.x;
    if (i >= n2) return;
    out[i] = out2[i] + b2[i & 1];
}

// ---------------------------------------------------------------------------
extern "C" void kernel_launch(void* const* d_in, const int* in_sizes, int n_in,
                              void* d_out, int out_size, void* d_ws, size_t ws_size,
                              hipStream_t stream)
{
    const float* x   = (const float*)d_in[0];
    const int*   ei  = (const int*)d_in[1];
    const float* W1  = (const float*)d_in[2];
    const float* as1 = (const float*)d_in[3];
    const float* ad1 = (const float*)d_in[4];
    const float* b1  = (const float*)d_in[5];
    const float* W2  = (const float*)d_in[6];
    const float* as2 = (const float*)d_in[7];
    const float* ad2 = (const float*)d_in[8];
    const float* b2p = (const float*)d_in[9];

    const int N  = in_sizes[0] / 128;   // 50000
    const int E  = in_sizes[1] / 2;     // 800000
    const int ET = E + N;               // + self loops

    // Workspace budget (~80.6 MB) -- MUST stay within ws_size; round-1 failure
    // was an overflow (123 MB) that corrupted the harness's pristine d_in copies.
    char* ws = (char*)d_ws;
    size_t off = 0;
    auto alloc = [&](size_t bytes) -> char* {
        char* p = ws + off;
        off = (off + bytes + 255) & ~(size_t)255;
        return p;
    };
    unsigned short* h1 = (unsigned short*)alloc((size_t)N * 256 * 2);  // bf16
    float* a_src1  = (float*)alloc((size_t)N * 4 * 4);
    float* a_dst1  = (float*)alloc((size_t)N * 4 * 4);
    float* denom1  = (float*)alloc((size_t)N * 4 * 4);
    float* out1    = (float*)alloc((size_t)N * 256 * 4);
    float* h2      = (float*)alloc((size_t)N * 2 * 4);
    float* a_src2v = (float*)alloc((size_t)N * 4);
    float* a_dst2v = (float*)alloc((size_t)N * 4);
    float* denom2  = (float*)alloc((size_t)N * 4);
    float* out2    = (float*)alloc((size_t)N * 2 * 4);

    // d_ws is poisoned 0xAA before every call: zero all accumulators
    hipMemsetAsync(denom1, 0, (size_t)N * 4 * 4, stream);
    hipMemsetAsync(out1,   0, (size_t)N * 256 * 4, stream);
    hipMemsetAsync(denom2, 0, (size_t)N * 4, stream);
    hipMemsetAsync(out2,   0, (size_t)N * 2 * 4, stream);

    gemm1_kernel<<<N / 4, 256, 0, stream>>>(x, W1, as1, ad1, h1, a_src1, a_dst1);
    edge_alpha1_kernel<<<(ET + 255) / 256, 256, 0, stream>>>(
        ei, E, ET, (const float4*)a_src1, (const float4*)a_dst1, denom1);
    aggregate1_kernel<<<ET, 256, 0, stream>>>(ei, E, h1, a_src1, a_dst1, denom1, out1);
    layer2_kernel<<<N, 256, 0, stream>>>(out1, b1, W2, as2, ad2, h2, a_src2v, a_dst2v);
    edge_alpha2_kernel<<<(ET + 255) / 256, 256, 0, stream>>>(ei, E, ET, a_src2v, a_dst2v, denom2);
    aggregate2_kernel<<<(ET + 255) / 256, 256, 0, stream>>>(ei, E, ET, h2, a_src2v, a_dst2v, denom2, out2);
    finalize_kernel<<<(N * 2 + 255) / 256, 256, 0, stream>>>(out2, b2p, (float*)d_out, N * 2);
}

// Round 4
// 752.452 us; speedup vs baseline: 1.7711x; 1.7711x over previous
//
#include <hip/hip_runtime.h>
#include <hip/hip_bf16.h>
#include <stdint.h>

#define NEG_SLOPE 0.2f
#define EPSV 1e-16f

static __device__ __forceinline__ float b2f(unsigned short u) {
    union { float f; uint32_t i; } v; v.i = ((uint32_t)u) << 16; return v.f;
}
static __device__ __forceinline__ unsigned short f2b(float f) {
    union { float f; uint32_t i; } v; v.f = f;
    uint32_t x = v.i;
    return (unsigned short)((x + 0x7FFFu + ((x >> 16) & 1u)) >> 16);
}

// ---------------------------------------------------------------------------
// Layer-1 GEMM: h1 = x @ W1^T  (x:[N,128] f32, W1:[256,128] f32 -> h1:[N,256] bf16)
// fused with attention dots a_src1/a_dst1 [N,4] (f32).
// Block = 256 threads, 8 nodes per block (halves W1 L2 traffic vs 4).
// Wave w == head w -> wave shuffle-reduce for the attention dots.
// ---------------------------------------------------------------------------
__global__ __launch_bounds__(256) void gemm1_kernel(
    const float* __restrict__ x,
    const float* __restrict__ W1,
    const float* __restrict__ att_src1,
    const float* __restrict__ att_dst1,
    unsigned short* __restrict__ h1,
    float* __restrict__ a_src1,
    float* __restrict__ a_dst1)
{
    __shared__ float xs[8][128];
    const int node0 = blockIdx.x * 8;
    const int t = threadIdx.x;

    // stage 8 x-rows (1024 f32) into LDS: each thread loads one float4
    const float4* xr = (const float4*)(x + (size_t)node0 * 128);
    float4 u = xr[t];
    int fl = t * 4;
    float* dst = &xs[fl >> 7][fl & 127];
    dst[0] = u.x; dst[1] = u.y; dst[2] = u.z; dst[3] = u.w;
    __syncthreads();

    const float4* wv = (const float4*)(W1 + (size_t)t * 128);
    float acc[8] = {0.f, 0.f, 0.f, 0.f, 0.f, 0.f, 0.f, 0.f};
    #pragma unroll 8
    for (int k4 = 0; k4 < 32; ++k4) {
        float4 w = wv[k4];
        int k0 = k4 * 4;
        float wf[4] = {w.x, w.y, w.z, w.w};
        #pragma unroll
        for (int i = 0; i < 4; ++i) {
            float wfi = wf[i];
            #pragma unroll
            for (int j = 0; j < 8; ++j)
                acc[j] += xs[j][k0 + i] * wfi;
        }
    }

    size_t base = (size_t)node0 * 256 + t;
    #pragma unroll
    for (int j = 0; j < 8; ++j)
        h1[base + (size_t)j * 256] = f2b(acc[j]);

    const float asw = att_src1[t];
    const float adw = att_dst1[t];
    const int lane = t & 63, head = t >> 6;
    #pragma unroll
    for (int j = 0; j < 8; ++j) {
        float ps = acc[j] * asw;
        float pd = acc[j] * adw;
        #pragma unroll
        for (int off = 32; off; off >>= 1) {
            ps += __shfl_xor(ps, off);
            pd += __shfl_xor(pd, off);
        }
        if (lane == 0) {
            a_src1[(size_t)(node0 + j) * 4 + head] = ps;
            a_dst1[(size_t)(node0 + j) * 4 + head] = pd;
        }
    }
}

// edges 0..E-1 from edge_index, edges E..ET-1 are self loops
static __device__ __forceinline__ void edge_sd(const int* __restrict__ ei,
                                               int e, int E, int& s, int& d) {
    if (e < E) { s = ei[e]; d = ei[E + e]; }
    else       { s = e - E; d = s; }
}

static __device__ __forceinline__ float edge_exp(float as, float ad) {
    float a = as + ad;
    a = a > 0.f ? a : NEG_SLOPE * a;
    return __expf(a);   // no max-subtraction: softmax shift-invariant, |a| is O(10)
}

// ---------------- CSR build (by destination) ----------------
__global__ void count_deg_kernel(const int* __restrict__ ei, int E, int ET,
                                 int* __restrict__ deg)
{
    int e = blockIdx.x * blockDim.x + threadIdx.x;
    if (e >= ET) return;
    int s, d; edge_sd(ei, e, E, s, d);
    atomicAdd(&deg[d], 1);
}

// single-block exclusive scan of deg[0..N) -> row_start[0..N], cursor copy
__global__ __launch_bounds__(1024) void scan_kernel(
    const int* __restrict__ deg, int* __restrict__ row_start,
    int* __restrict__ cursor, int N)
{
    __shared__ int sums[1024];
    int t = threadIdx.x;
    int chunk = (N + 1023) >> 10;
    int lo = t * chunk, hi = lo + chunk; if (hi > N) hi = N; if (lo > N) lo = N;
    int s = 0;
    for (int i = lo; i < hi; ++i) s += deg[i];
    sums[t] = s;
    __syncthreads();
    for (int off = 1; off < 1024; off <<= 1) {
        int v = 0;
        if (t >= off) v = sums[t - off];
        __syncthreads();
        if (t >= off) sums[t] += v;
        __syncthreads();
    }
    int base = sums[t] - s;   // exclusive prefix
    for (int i = lo; i < hi; ++i) {
        row_start[i] = base;
        cursor[i]    = base;
        base += deg[i];
    }
    if (t == 1023) row_start[N] = sums[1023];
}

__global__ void scatter_kernel(const int* __restrict__ ei, int E, int ET,
                               int* __restrict__ cursor, int* __restrict__ csr_src)
{
    int e = blockIdx.x * blockDim.x + threadIdx.x;
    if (e >= ET) return;
    int s, d; edge_sd(ei, e, E, s, d);
    int p = atomicAdd(&cursor[d], 1);
    csr_src[p] = s;
}

// ---------------- Layer-1 aggregate: gather over CSR, zero atomics ----------
// Block = dst node, thread t = channel t, head h = t>>6.
// Pass 1: softmax denominator per head; pass 2: weighted gather of h1 rows.
__global__ __launch_bounds__(256) void aggregate1_csr_kernel(
    const int* __restrict__ row_start, const int* __restrict__ csr_src,
    const unsigned short* __restrict__ h1,
    const float* __restrict__ a_src1, const float* __restrict__ a_dst1,
    unsigned short* __restrict__ out1)
{
    int n = blockIdx.x, t = threadIdx.x, h = t >> 6;
    int lo = row_start[n], hi = row_start[n + 1];
    float adh = a_dst1[(size_t)n * 4 + h];

    float denom = 0.f;
    for (int i = lo; i < hi; ++i) {
        int s = csr_src[i];
        denom += edge_exp(a_src1[(size_t)s * 4 + h], adh);
    }
    float acc = 0.f;
    for (int i = lo; i < hi; ++i) {
        int s = csr_src[i];
        float ex = edge_exp(a_src1[(size_t)s * 4 + h], adh);
        acc += b2f(h1[(size_t)s * 256 + t]) * ex;
    }
    out1[(size_t)n * 256 + t] = f2b(acc / (denom + EPSV));
}

// ---------------- Layer-2 GEMM: h2 = relu(out1+b1) @ W2^T + attention dots --
__global__ __launch_bounds__(256) void layer2_kernel(
    const unsigned short* __restrict__ out1, const float* __restrict__ b1,
    const float* __restrict__ W2,
    const float* __restrict__ as2, const float* __restrict__ ad2,
    float* __restrict__ h2, float* __restrict__ a_src2, float* __restrict__ a_dst2)
{
    int n = blockIdx.x, t = threadIdx.x;
    float v = b2f(out1[(size_t)n * 256 + t]) + b1[t];
    v = v > 0.f ? v : 0.f;
    float p0 = v * W2[t];
    float p1 = v * W2[256 + t];
    #pragma unroll
    for (int off = 32; off; off >>= 1) {
        p0 += __shfl_xor(p0, off);
        p1 += __shfl_xor(p1, off);
    }
    __shared__ float s0[4], s1[4];
    int lane = t & 63, w = t >> 6;
    if (lane == 0) { s0[w] = p0; s1[w] = p1; }
    __syncthreads();
    if (t == 0) {
        float h0  = s0[0] + s0[1] + s0[2] + s0[3];
        float h1v = s1[0] + s1[1] + s1[2] + s1[3];
        h2[(size_t)n * 2]     = h0;
        h2[(size_t)n * 2 + 1] = h1v;
        a_src2[n] = h0 * as2[0] + h1v * as2[1];
        a_dst2[n] = h0 * ad2[0] + h1v * ad2[1];
    }
}

// ---------------- Layer-2 aggregate: wave per dst node, fused bias ----------
__global__ __launch_bounds__(256) void aggregate2_csr_kernel(
    const int* __restrict__ row_start, const int* __restrict__ csr_src,
    const float* __restrict__ h2,
    const float* __restrict__ a_src2, const float* __restrict__ a_dst2,
    const float* __restrict__ b2, float* __restrict__ out, int N)
{
    int w = threadIdx.x >> 6, lane = threadIdx.x & 63;
    int n = blockIdx.x * 4 + w;
    if (n >= N) return;
    int lo = row_start[n], hi = row_start[n + 1];
    float ad = a_dst2[n];
    float den = 0.f, num0 = 0.f, num1 = 0.f;
    for (int i = lo + lane; i < hi; i += 64) {
        int s = csr_src[i];
        float ex = edge_exp(a_src2[s], ad);
        float2 hh = ((const float2*)h2)[s];
        den  += ex;
        num0 += ex * hh.x;
        num1 += ex * hh.y;
    }
    #pragma unroll
    for (int off = 32; off; off >>= 1) {
        den  += __shfl_xor(den, off);
        num0 += __shfl_xor(num0, off);
        num1 += __shfl_xor(num1, off);
    }
    if (lane == 0) {
        float inv = 1.f / (den + EPSV);
        out[(size_t)n * 2]     = num0 * inv + b2[0];
        out[(size_t)n * 2 + 1] = num1 * inv + b2[1];
    }
}

// ---------------------------------------------------------------------------
extern "C" void kernel_launch(void* const* d_in, const int* in_sizes, int n_in,
                              void* d_out, int out_size, void* d_ws, size_t ws_size,
                              hipStream_t stream)
{
    const float* x   = (const float*)d_in[0];
    const int*   ei  = (const int*)d_in[1];
    const float* W1  = (const float*)d_in[2];
    const float* as1 = (const float*)d_in[3];
    const float* ad1 = (const float*)d_in[4];
    const float* b1  = (const float*)d_in[5];
    const float* W2  = (const float*)d_in[6];
    const float* as2 = (const float*)d_in[7];
    const float* ad2 = (const float*)d_in[8];
    const float* b2p = (const float*)d_in[9];

    const int N  = in_sizes[0] / 128;   // 50000
    const int E  = in_sizes[1] / 2;     // 800000
    const int ET = E + N;               // + self loops

    // Workspace ~57.5 MB (ws overflow at 123 MB corrupted pristine inputs in R1;
    // 80.6 MB passed in R2 -- stay well under).
    char* ws = (char*)d_ws;
    size_t off = 0;
    auto alloc = [&](size_t bytes) -> char* {
        char* p = ws + off;
        off = (off + bytes + 255) & ~(size_t)255;
        return p;
    };
    unsigned short* h1   = (unsigned short*)alloc((size_t)N * 256 * 2);  // bf16
    unsigned short* out1 = (unsigned short*)alloc((size_t)N * 256 * 2);  // bf16
    float* a_src1  = (float*)alloc((size_t)N * 4 * 4);
    float* a_dst1  = (float*)alloc((size_t)N * 4 * 4);
    float* h2      = (float*)alloc((size_t)N * 2 * 4);
    float* a_src2v = (float*)alloc((size_t)N * 4);
    float* a_dst2v = (float*)alloc((size_t)N * 4);
    int*   deg     = (int*)alloc((size_t)N * 4);
    int*   row_st  = (int*)alloc((size_t)(N + 1) * 4);
    int*   cursor  = (int*)alloc((size_t)N * 4);
    int*   csr_src = (int*)alloc((size_t)ET * 4);

    hipMemsetAsync(deg, 0, (size_t)N * 4, stream);

    gemm1_kernel<<<N / 8, 256, 0, stream>>>(x, W1, as1, ad1, h1, a_src1, a_dst1);
    count_deg_kernel<<<(ET + 255) / 256, 256, 0, stream>>>(ei, E, ET, deg);
    scan_kernel<<<1, 1024, 0, stream>>>(deg, row_st, cursor, N);
    scatter_kernel<<<(ET + 255) / 256, 256, 0, stream>>>(ei, E, ET, cursor, csr_src);
    aggregate1_csr_kernel<<<N, 256, 0, stream>>>(row_st, csr_src, h1, a_src1, a_dst1, out1);
    layer2_kernel<<<N, 256, 0, stream>>>(out1, b1, W2, as2, ad2, h2, a_src2v, a_dst2v);
    aggregate2_csr_kernel<<<(N + 3) / 4, 256, 0, stream>>>(
        row_st, csr_src, h2, a_src2v, a_dst2v, b2p, (float*)d_out, N);
}

// Round 5
// 485.715 us; speedup vs baseline: 2.7437x; 1.5492x over previous
//
#include <hip/hip_runtime.h>
#include <hip/hip_bf16.h>
#include <stdint.h>

#define NEG_SLOPE 0.2f
#define EPSV 1e-16f

static __device__ __forceinline__ float b2f(unsigned short u) {
    union { float f; uint32_t i; } v; v.i = ((uint32_t)u) << 16; return v.f;
}
static __device__ __forceinline__ unsigned short f2b(float f) {
    union { float f; uint32_t i; } v; v.f = f;
    uint32_t x = v.i;
    return (unsigned short)((x + 0x7FFFu + ((x >> 16) & 1u)) >> 16);
}

// ---------------------------------------------------------------------------
// Layer-1 GEMM: h1 = x @ W1^T  (x:[N,128] f32, W1:[256,128] f32 -> h1:[N,256] bf16)
// fused with attention dots a_src1/a_dst1 [N,4] (f32).
// Block = 256 threads, 8 nodes per block. Wave w == head w -> wave reduce.
// ---------------------------------------------------------------------------
__global__ __launch_bounds__(256) void gemm1_kernel(
    const float* __restrict__ x,
    const float* __restrict__ W1,
    const float* __restrict__ att_src1,
    const float* __restrict__ att_dst1,
    unsigned short* __restrict__ h1,
    float* __restrict__ a_src1,
    float* __restrict__ a_dst1)
{
    __shared__ float xs[8][128];
    const int node0 = blockIdx.x * 8;
    const int t = threadIdx.x;

    const float4* xr = (const float4*)(x + (size_t)node0 * 128);
    float4 u = xr[t];
    int fl = t * 4;
    float* dst = &xs[fl >> 7][fl & 127];
    dst[0] = u.x; dst[1] = u.y; dst[2] = u.z; dst[3] = u.w;
    __syncthreads();

    const float4* wv = (const float4*)(W1 + (size_t)t * 128);
    float acc[8] = {0.f, 0.f, 0.f, 0.f, 0.f, 0.f, 0.f, 0.f};
    #pragma unroll 8
    for (int k4 = 0; k4 < 32; ++k4) {
        float4 w = wv[k4];
        int k0 = k4 * 4;
        float wf[4] = {w.x, w.y, w.z, w.w};
        #pragma unroll
        for (int i = 0; i < 4; ++i) {
            float wfi = wf[i];
            #pragma unroll
            for (int j = 0; j < 8; ++j)
                acc[j] += xs[j][k0 + i] * wfi;
        }
    }

    size_t base = (size_t)node0 * 256 + t;
    #pragma unroll
    for (int j = 0; j < 8; ++j)
        h1[base + (size_t)j * 256] = f2b(acc[j]);

    const float asw = att_src1[t];
    const float adw = att_dst1[t];
    const int lane = t & 63, head = t >> 6;
    #pragma unroll
    for (int j = 0; j < 8; ++j) {
        float ps = acc[j] * asw;
        float pd = acc[j] * adw;
        #pragma unroll
        for (int off = 32; off; off >>= 1) {
            ps += __shfl_xor(ps, off);
            pd += __shfl_xor(pd, off);
        }
        if (lane == 0) {
            a_src1[(size_t)(node0 + j) * 4 + head] = ps;
            a_dst1[(size_t)(node0 + j) * 4 + head] = pd;
        }
    }
}

// edges 0..E-1 from edge_index, edges E..ET-1 are self loops
static __device__ __forceinline__ void edge_sd(const int* __restrict__ ei,
                                               int e, int E, int& s, int& d) {
    if (e < E) { s = ei[e]; d = ei[E + e]; }
    else       { s = e - E; d = s; }
}

static __device__ __forceinline__ float edge_exp(float as, float ad) {
    float a = as + ad;
    a = a > 0.f ? a : NEG_SLOPE * a;
    return __expf(a);   // no max-subtraction: softmax shift-invariant, |a| is O(10)
}

// ---------------- CSR build (by destination) ----------------
__global__ void count_deg_kernel(const int* __restrict__ ei, int E, int ET,
                                 int* __restrict__ deg)
{
    int e = blockIdx.x * blockDim.x + threadIdx.x;
    if (e >= ET) return;
    int s, d; edge_sd(ei, e, E, s, d);
    atomicAdd(&deg[d], 1);
}

__global__ __launch_bounds__(1024) void scan_kernel(
    const int* __restrict__ deg, int* __restrict__ row_start,
    int* __restrict__ cursor, int N)
{
    __shared__ int sums[1024];
    int t = threadIdx.x;
    int chunk = (N + 1023) >> 10;
    int lo = t * chunk, hi = lo + chunk; if (hi > N) hi = N; if (lo > N) lo = N;
    int s = 0;
    for (int i = lo; i < hi; ++i) s += deg[i];
    sums[t] = s;
    __syncthreads();
    for (int off = 1; off < 1024; off <<= 1) {
        int v = 0;
        if (t >= off) v = sums[t - off];
        __syncthreads();
        if (t >= off) sums[t] += v;
        __syncthreads();
    }
    int base = sums[t] - s;   // exclusive prefix
    for (int i = lo; i < hi; ++i) {
        row_start[i] = base;
        cursor[i]    = base;
        base += deg[i];
    }
    if (t == 1023) row_start[N] = sums[1023];
}

__global__ void scatter_kernel(const int* __restrict__ ei, int E, int ET,
                               int* __restrict__ cursor, int* __restrict__ csr_src)
{
    int e = blockIdx.x * blockDim.x + threadIdx.x;
    if (e >= ET) return;
    int s, d; edge_sd(ei, e, E, s, d);
    int p = atomicAdd(&cursor[d], 1);
    csr_src[p] = s;
}

// ---------------------------------------------------------------------------
// Fused layer-1 aggregate + layer-2 GEMM.
// Block = dst node n. 4 waves split the edge list (i = lo+w, step 4); each
// lane covers channels 4*lane..4*lane+3 (uint2 = 4 bf16 of the h1 row), all
// within head lane>>4. Single pass: numerator and denominator together.
// Then bias+relu+W2 dots in-block -> h2[n], a_src2[n], a_dst2[n].
// ---------------------------------------------------------------------------
__global__ __launch_bounds__(256) void agg1_layer2_kernel(
    const int* __restrict__ row_start, const int* __restrict__ csr_src,
    const uint2* __restrict__ h1v,          // row n = h1v[n*64 .. n*64+63]
    const float* __restrict__ a_src1, const float* __restrict__ a_dst1,
    const float* __restrict__ b1, const float* __restrict__ W2,
    const float* __restrict__ as2, const float* __restrict__ ad2,
    float* __restrict__ h2, float* __restrict__ a_src2, float* __restrict__ a_dst2)
{
    __shared__ float sacc[4][256];
    __shared__ float sden[4][4];
    __shared__ float red0[4], red1[4];

    const int n = blockIdx.x, t = threadIdx.x;
    const int w = t >> 6, lane = t & 63;
    const int h = lane >> 4;                 // head of this lane's 4 channels
    const int lo = row_start[n], hi = row_start[n + 1];
    const float adh = a_dst1[(size_t)n * 4 + h];

    float a0 = 0.f, a1 = 0.f, a2 = 0.f, a3 = 0.f, den = 0.f;
    int i = lo + w;
    int sn = (i < hi) ? csr_src[i] : 0;
    for (; i < hi; i += 4) {
        int s = sn;
        int inext = i + 4;
        if (inext < hi) sn = csr_src[inext];
        float ex = edge_exp(a_src1[(size_t)s * 4 + h], adh);
        uint2 r = h1v[(size_t)s * 64 + lane];
        a0 += ex * b2f((unsigned short)(r.x & 0xFFFF));
        a1 += ex * b2f((unsigned short)(r.x >> 16));
        a2 += ex * b2f((unsigned short)(r.y & 0xFFFF));
        a3 += ex * b2f((unsigned short)(r.y >> 16));
        den += ex;
    }
    float* sa = &sacc[w][lane * 4];
    sa[0] = a0; sa[1] = a1; sa[2] = a2; sa[3] = a3;
    if ((lane & 15) == 0) sden[w][h] = den;  // lanes of same head carry equal den
    __syncthreads();

    // thread t = output channel c
    const int c = t, hh = c >> 6;
    float acc = sacc[0][c] + sacc[1][c] + sacc[2][c] + sacc[3][c];
    float dn  = sden[0][hh] + sden[1][hh] + sden[2][hh] + sden[3][hh];
    float v = acc / (dn + EPSV) + b1[c];
    v = v > 0.f ? v : 0.f;

    float p0 = v * W2[c];
    float p1 = v * W2[256 + c];
    #pragma unroll
    for (int off = 32; off; off >>= 1) {
        p0 += __shfl_xor(p0, off);
        p1 += __shfl_xor(p1, off);
    }
    if (lane == 0) { red0[w] = p0; red1[w] = p1; }
    __syncthreads();
    if (t == 0) {
        float h0  = red0[0] + red0[1] + red0[2] + red0[3];
        float h1s = red1[0] + red1[1] + red1[2] + red1[3];
        h2[(size_t)n * 2]     = h0;
        h2[(size_t)n * 2 + 1] = h1s;
        a_src2[n] = h0 * as2[0] + h1s * as2[1];
        a_dst2[n] = h0 * ad2[0] + h1s * ad2[1];
    }
}

// ---------------- Layer-2 aggregate: wave per dst node, fused bias ----------
__global__ __launch_bounds__(256) void aggregate2_csr_kernel(
    const int* __restrict__ row_start, const int* __restrict__ csr_src,
    const float* __restrict__ h2,
    const float* __restrict__ a_src2, const float* __restrict__ a_dst2,
    const float* __restrict__ b2, float* __restrict__ out, int N)
{
    int w = threadIdx.x >> 6, lane = threadIdx.x & 63;
    int n = blockIdx.x * 4 + w;
    if (n >= N) return;
    int lo = row_start[n], hi = row_start[n + 1];
    float ad = a_dst2[n];
    float den = 0.f, num0 = 0.f, num1 = 0.f;
    for (int i = lo + lane; i < hi; i += 64) {
        int s = csr_src[i];
        float ex = edge_exp(a_src2[s], ad);
        float2 hh = ((const float2*)h2)[s];
        den  += ex;
        num0 += ex * hh.x;
        num1 += ex * hh.y;
    }
    #pragma unroll
    for (int off = 32; off; off >>= 1) {
        den  += __shfl_xor(den, off);
        num0 += __shfl_xor(num0, off);
        num1 += __shfl_xor(num1, off);
    }
    if (lane == 0) {
        float inv = 1.f / (den + EPSV);
        out[(size_t)n * 2]     = num0 * inv + b2[0];
        out[(size_t)n * 2 + 1] = num1 * inv + b2[1];
    }
}

// ---------------------------------------------------------------------------
extern "C" void kernel_launch(void* const* d_in, const int* in_sizes, int n_in,
                              void* d_out, int out_size, void* d_ws, size_t ws_size,
                              hipStream_t stream)
{
    const float* x   = (const float*)d_in[0];
    const int*   ei  = (const int*)d_in[1];
    const float* W1  = (const float*)d_in[2];
    const float* as1 = (const float*)d_in[3];
    const float* ad1 = (const float*)d_in[4];
    const float* b1  = (const float*)d_in[5];
    const float* W2  = (const float*)d_in[6];
    const float* as2 = (const float*)d_in[7];
    const float* ad2 = (const float*)d_in[8];
    const float* b2p = (const float*)d_in[9];

    const int N  = in_sizes[0] / 128;   // 50000
    const int E  = in_sizes[1] / 2;     // 800000
    const int ET = E + N;               // + self loops

    // Workspace ~32 MB (ws overflow at 123 MB corrupted pristine inputs in R1).
    char* ws = (char*)d_ws;
    size_t off = 0;
    auto alloc = [&](size_t bytes) -> char* {
        char* p = ws + off;
        off = (off + bytes + 255) & ~(size_t)255;
        return p;
    };
    unsigned short* h1 = (unsigned short*)alloc((size_t)N * 256 * 2);  // bf16
    float* a_src1  = (float*)alloc((size_t)N * 4 * 4);
    float* a_dst1  = (float*)alloc((size_t)N * 4 * 4);
    float* h2      = (float*)alloc((size_t)N * 2 * 4);
    float* a_src2v = (float*)alloc((size_t)N * 4);
    float* a_dst2v = (float*)alloc((size_t)N * 4);
    int*   deg     = (int*)alloc((size_t)N * 4);
    int*   row_st  = (int*)alloc((size_t)(N + 1) * 4);
    int*   cursor  = (int*)alloc((size_t)N * 4);
    int*   csr_src = (int*)alloc((size_t)ET * 4);

    hipMemsetAsync(deg, 0, (size_t)N * 4, stream);

    gemm1_kernel<<<N / 8, 256, 0, stream>>>(x, W1, as1, ad1, h1, a_src1, a_dst1);
    count_deg_kernel<<<(ET + 255) / 256, 256, 0, stream>>>(ei, E, ET, deg);
    scan_kernel<<<1, 1024, 0, stream>>>(deg, row_st, cursor, N);
    scatter_kernel<<<(ET + 255) / 256, 256, 0, stream>>>(ei, E, ET, cursor, csr_src);
    agg1_layer2_kernel<<<N, 256, 0, stream>>>(
        row_st, csr_src, (const uint2*)h1, a_src1, a_dst1,
        b1, W2, as2, ad2, h2, a_src2v, a_dst2v);
    aggregate2_csr_kernel<<<(N + 3) / 4, 256, 0, stream>>>(
        row_st, csr_src, h2, a_src2v, a_dst2v, b2p, (float*)d_out, N);
}

// Round 6
// 451.414 us; speedup vs baseline: 2.9522x; 1.0760x over previous
//
#include <hip/hip_runtime.h>
#include <hip/hip_bf16.h>
#include <stdint.h>

#define NEG_SLOPE 0.2f
#define EPSV 1e-16f

typedef __attribute__((ext_vector_type(8))) short bf16x8;   // 8 bf16 = 4 VGPRs
typedef __attribute__((ext_vector_type(4))) float f32x4;

static __device__ __forceinline__ float b2f(unsigned short u) {
    union { float f; uint32_t i; } v; v.i = ((uint32_t)u) << 16; return v.f;
}
static __device__ __forceinline__ unsigned short f2b(float f) {
    union { float f; uint32_t i; } v; v.f = f;
    uint32_t x = v.i;
    return (unsigned short)((x + 0x7FFFu + ((x >> 16) & 1u)) >> 16);
}
static __device__ __forceinline__ uint32_t f2b_pk(float a, float b) {
    return (uint32_t)f2b(a) | ((uint32_t)f2b(b) << 16);
}

// edges 0..E-1 from edge_index, edges E..ET-1 are self loops
static __device__ __forceinline__ void edge_sd(const int* __restrict__ ei,
                                               int e, int E, int& s, int& d) {
    if (e < E) { s = ei[e]; d = ei[E + e]; }
    else       { s = e - E; d = s; }
}

static __device__ __forceinline__ float edge_exp(float as, float ad) {
    float a = as + ad;
    a = a > 0.f ? a : NEG_SLOPE * a;
    return __expf(a);   // no max-subtraction: softmax shift-invariant, |a| is O(10)
}

// ---------------------------------------------------------------------------
// prep: (a) x -> bf16 (blocks [0, nblk_x))
//       (b) degree count for CSR (blocks [nblk_x, nblk_x+nblk_cnt))
//       (c) W1 -> bf16 (block nblk_x+nblk_cnt)
//       (d) w_att[v][k] = sum_c att_{src|dst}[h*64+c] * W1[(h*64+c)*128+k],
//           v = 2h + is_dst (block nblk_x+nblk_cnt+1)
// ---------------------------------------------------------------------------
__global__ __launch_bounds__(256) void prep_kernel(
    const float* __restrict__ x, const float* __restrict__ W1,
    const float* __restrict__ att_src1, const float* __restrict__ att_dst1,
    const int* __restrict__ ei, int E, int ET,
    uint32_t* __restrict__ xb, uint32_t* __restrict__ W1b,
    float* __restrict__ w_att, int* __restrict__ deg,
    int nblk_x, int nblk_cnt)
{
    int b = blockIdx.x, t = threadIdx.x;
    if (b < nblk_x) {
        int i = b * 256 + t;
        float2 v = ((const float2*)x)[i];
        xb[i] = f2b_pk(v.x, v.y);
    } else if (b < nblk_x + nblk_cnt) {
        int e = (b - nblk_x) * 256 + t;
        if (e < ET) {
            int s, d; edge_sd(ei, e, E, s, d);
            (void)s;
            atomicAdd(&deg[d], 1);
        }
    } else if (b == nblk_x + nblk_cnt) {
        for (int j = t; j < 16384; j += 256) {   // 256*128/2 packed pairs
            float2 v = ((const float2*)W1)[j];
            W1b[j] = f2b_pk(v.x, v.y);
        }
    } else {
        for (int idx = t; idx < 1024; idx += 256) {
            int vec = idx >> 7, k = idx & 127;
            int h = vec >> 1;
            const float* att = (vec & 1) ? att_dst1 : att_src1;
            float s = 0.f;
            for (int c = 0; c < 64; ++c)
                s += att[h * 64 + c] * W1[(size_t)(h * 64 + c) * 128 + k];
            w_att[idx] = s;
        }
    }
}

// ---------------------------------------------------------------------------
// a_src1[n,h] = x[n,:] . w_att[2h];  a_dst1[n,h] = x[n,:] . w_att[2h+1]
// wave per node, 4 nodes/block.
// ---------------------------------------------------------------------------
__global__ __launch_bounds__(256) void attdot_kernel(
    const float* __restrict__ x, const float* __restrict__ w_att,
    float* __restrict__ a_src1, float* __restrict__ a_dst1)
{
    int w = threadIdx.x >> 6, lane = threadIdx.x & 63;
    int n = blockIdx.x * 4 + w;
    float x0 = x[(size_t)n * 128 + lane];
    float x1 = x[(size_t)n * 128 + 64 + lane];
    float p[8];
    #pragma unroll
    for (int v = 0; v < 8; ++v)
        p[v] = x0 * w_att[v * 128 + lane] + x1 * w_att[v * 128 + 64 + lane];
    #pragma unroll
    for (int off = 32; off; off >>= 1) {
        #pragma unroll
        for (int v = 0; v < 8; ++v) p[v] += __shfl_xor(p[v], off);
    }
    if (lane == 0) {
        #pragma unroll
        for (int h = 0; h < 4; ++h) {
            a_src1[(size_t)n * 4 + h] = p[2 * h];
            a_dst1[(size_t)n * 4 + h] = p[2 * h + 1];
        }
    }
}

// ---------------------------------------------------------------------------
// h1 = xb @ W1b^T via MFMA bf16. Wave tile: 32 nodes x 256 channels, K=128.
// A[m=lane&15][k=quad*8+j]; B likewise with n=lane&15 (W1 natural layout = B^T).
// D: m = quad*4 + reg, n = lane&15.
// ---------------------------------------------------------------------------
__global__ __launch_bounds__(256) void gemm1_mfma_kernel(
    const short* __restrict__ xb, const short* __restrict__ W1b,
    unsigned short* __restrict__ h1, int N)
{
    const int t = threadIdx.x;
    const int wv = t >> 6, lane = t & 63;
    const int l15 = lane & 15, quad = lane >> 4;
    const int m0 = blockIdx.x * 128 + wv * 32;

    bf16x8 A[2][4];
    #pragma unroll
    for (int ms = 0; ms < 2; ++ms) {
        int m = m0 + ms * 16 + l15;
        int mr = m < N ? m : N - 1;
        const short* ap = xb + (size_t)mr * 128 + quad * 8;
        #pragma unroll
        for (int kk = 0; kk < 4; ++kk)
            A[ms][kk] = *(const bf16x8*)(ap + kk * 32);
    }

    f32x4 acc[2][16];
    #pragma unroll
    for (int ms = 0; ms < 2; ++ms)
        #pragma unroll
        for (int ct = 0; ct < 16; ++ct)
            acc[ms][ct] = (f32x4){0.f, 0.f, 0.f, 0.f};

    #pragma unroll
    for (int kk = 0; kk < 4; ++kk) {
        bf16x8 B[16];
        const short* bp = W1b + (size_t)l15 * 128 + kk * 32 + quad * 8;
        #pragma unroll
        for (int ct = 0; ct < 16; ++ct)
            B[ct] = *(const bf16x8*)(bp + (size_t)ct * 16 * 128);
        #pragma unroll
        for (int ct = 0; ct < 16; ++ct) {
            acc[0][ct] = __builtin_amdgcn_mfma_f32_16x16x32_bf16(A[0][kk], B[ct], acc[0][ct], 0, 0, 0);
            acc[1][ct] = __builtin_amdgcn_mfma_f32_16x16x32_bf16(A[1][kk], B[ct], acc[1][ct], 0, 0, 0);
        }
    }

    #pragma unroll
    for (int ms = 0; ms < 2; ++ms) {
        #pragma unroll
        for (int r = 0; r < 4; ++r) {
            int m = m0 + ms * 16 + quad * 4 + r;
            if (m < N) {
                unsigned short* hp = h1 + (size_t)m * 256 + l15;
                #pragma unroll
                for (int ct = 0; ct < 16; ++ct)
                    hp[ct * 16] = f2b(acc[ms][ct][r]);
            }
        }
    }
}

// ---------------- CSR scan + scatter ----------------
__global__ __launch_bounds__(1024) void scan_kernel(
    const int* __restrict__ deg, int* __restrict__ row_start,
    int* __restrict__ cursor, int N)
{
    __shared__ int sums[1024];
    int t = threadIdx.x;
    int chunk = (N + 1023) >> 10;
    int lo = t * chunk, hi = lo + chunk; if (hi > N) hi = N; if (lo > N) lo = N;
    int s = 0;
    for (int i = lo; i < hi; ++i) s += deg[i];
    sums[t] = s;
    __syncthreads();
    for (int off = 1; off < 1024; off <<= 1) {
        int v = 0;
        if (t >= off) v = sums[t - off];
        __syncthreads();
        if (t >= off) sums[t] += v;
        __syncthreads();
    }
    int base = sums[t] - s;   // exclusive prefix
    for (int i = lo; i < hi; ++i) {
        row_start[i] = base;
        cursor[i]    = base;
        base += deg[i];
    }
    if (t == 1023) row_start[N] = sums[1023];
}

__global__ void scatter_kernel(const int* __restrict__ ei, int E, int ET,
                               int* __restrict__ cursor, int* __restrict__ csr_src)
{
    int e = blockIdx.x * blockDim.x + threadIdx.x;
    if (e >= ET) return;
    int s, d; edge_sd(ei, e, E, s, d);
    int p = atomicAdd(&cursor[d], 1);
    csr_src[p] = s;
}

// ---------------------------------------------------------------------------
// Fused layer-1 aggregate + layer-2 GEMM (unchanged from R4).
// ---------------------------------------------------------------------------
__global__ __launch_bounds__(256) void agg1_layer2_kernel(
    const int* __restrict__ row_start, const int* __restrict__ csr_src,
    const uint2* __restrict__ h1v,
    const float* __restrict__ a_src1, const float* __restrict__ a_dst1,
    const float* __restrict__ b1, const float* __restrict__ W2,
    const float* __restrict__ as2, const float* __restrict__ ad2,
    float* __restrict__ h2, float* __restrict__ a_src2, float* __restrict__ a_dst2)
{
    __shared__ float sacc[4][256];
    __shared__ float sden[4][4];
    __shared__ float red0[4], red1[4];

    const int n = blockIdx.x, t = threadIdx.x;
    const int w = t >> 6, lane = t & 63;
    const int h = lane >> 4;
    const int lo = row_start[n], hi = row_start[n + 1];
    const float adh = a_dst1[(size_t)n * 4 + h];

    float a0 = 0.f, a1 = 0.f, a2 = 0.f, a3 = 0.f, den = 0.f;
    int i = lo + w;
    int sn = (i < hi) ? csr_src[i] : 0;
    for (; i < hi; i += 4) {
        int s = sn;
        int inext = i + 4;
        if (inext < hi) sn = csr_src[inext];
        float ex = edge_exp(a_src1[(size_t)s * 4 + h], adh);
        uint2 r = h1v[(size_t)s * 64 + lane];
        a0 += ex * b2f((unsigned short)(r.x & 0xFFFF));
        a1 += ex * b2f((unsigned short)(r.x >> 16));
        a2 += ex * b2f((unsigned short)(r.y & 0xFFFF));
        a3 += ex * b2f((unsigned short)(r.y >> 16));
        den += ex;
    }
    float* sa = &sacc[w][lane * 4];
    sa[0] = a0; sa[1] = a1; sa[2] = a2; sa[3] = a3;
    if ((lane & 15) == 0) sden[w][h] = den;
    __syncthreads();

    const int c = t, hh = c >> 6;
    float acc = sacc[0][c] + sacc[1][c] + sacc[2][c] + sacc[3][c];
    float dn  = sden[0][hh] + sden[1][hh] + sden[2][hh] + sden[3][hh];
    float v = acc / (dn + EPSV) + b1[c];
    v = v > 0.f ? v : 0.f;

    float p0 = v * W2[c];
    float p1 = v * W2[256 + c];
    #pragma unroll
    for (int off = 32; off; off >>= 1) {
        p0 += __shfl_xor(p0, off);
        p1 += __shfl_xor(p1, off);
    }
    if (lane == 0) { red0[w] = p0; red1[w] = p1; }
    __syncthreads();
    if (t == 0) {
        float h0  = red0[0] + red0[1] + red0[2] + red0[3];
        float h1s = red1[0] + red1[1] + red1[2] + red1[3];
        h2[(size_t)n * 2]     = h0;
        h2[(size_t)n * 2 + 1] = h1s;
        a_src2[n] = h0 * as2[0] + h1s * as2[1];
        a_dst2[n] = h0 * ad2[0] + h1s * ad2[1];
    }
}

// ---------------- Layer-2 aggregate: wave per dst node, fused bias ----------
__global__ __launch_bounds__(256) void aggregate2_csr_kernel(
    const int* __restrict__ row_start, const int* __restrict__ csr_src,
    const float* __restrict__ h2,
    const float* __restrict__ a_src2, const float* __restrict__ a_dst2,
    const float* __restrict__ b2, float* __restrict__ out, int N)
{
    int w = threadIdx.x >> 6, lane = threadIdx.x & 63;
    int n = blockIdx.x * 4 + w;
    if (n >= N) return;
    int lo = row_start[n], hi = row_start[n + 1];
    float ad = a_dst2[n];
    float den = 0.f, num0 = 0.f, num1 = 0.f;
    for (int i = lo + lane; i < hi; i += 64) {
        int s = csr_src[i];
        float ex = edge_exp(a_src2[s], ad);
        float2 hh = ((const float2*)h2)[s];
        den  += ex;
        num0 += ex * hh.x;
        num1 += ex * hh.y;
    }
    #pragma unroll
    for (int off = 32; off; off >>= 1) {
        den  += __shfl_xor(den, off);
        num0 += __shfl_xor(num0, off);
        num1 += __shfl_xor(num1, off);
    }
    if (lane == 0) {
        float inv = 1.f / (den + EPSV);
        out[(size_t)n * 2]     = num0 * inv + b2[0];
        out[(size_t)n * 2 + 1] = num1 * inv + b2[1];
    }
}

// ---------------------------------------------------------------------------
extern "C" void kernel_launch(void* const* d_in, const int* in_sizes, int n_in,
                              void* d_out, int out_size, void* d_ws, size_t ws_size,
                              hipStream_t stream)
{
    const float* x   = (const float*)d_in[0];
    const int*   ei  = (const int*)d_in[1];
    const float* W1  = (const float*)d_in[2];
    const float* as1 = (const float*)d_in[3];
    const float* ad1 = (const float*)d_in[4];
    const float* b1  = (const float*)d_in[5];
    const float* W2  = (const float*)d_in[6];
    const float* as2 = (const float*)d_in[7];
    const float* ad2 = (const float*)d_in[8];
    const float* b2p = (const float*)d_in[9];

    const int N  = in_sizes[0] / 128;   // 50000
    const int E  = in_sizes[1] / 2;     // 800000
    const int ET = E + N;               // + self loops

    // Workspace ~45 MB (overflow at 123 MB corrupted pristine inputs in R1).
    char* ws = (char*)d_ws;
    size_t off = 0;
    auto alloc = [&](size_t bytes) -> char* {
        char* p = ws + off;
        off = (off + bytes + 255) & ~(size_t)255;
        return p;
    };
    uint32_t* xb   = (uint32_t*)alloc((size_t)N * 64 * 4);        // x as bf16 pairs
    uint32_t* W1b  = (uint32_t*)alloc((size_t)16384 * 4);         // W1 as bf16 pairs
    float* w_att   = (float*)alloc((size_t)1024 * 4);             // 8 x 128
    unsigned short* h1 = (unsigned short*)alloc((size_t)N * 256 * 2);
    float* a_src1  = (float*)alloc((size_t)N * 4 * 4);
    float* a_dst1  = (float*)alloc((size_t)N * 4 * 4);
    float* h2      = (float*)alloc((size_t)N * 2 * 4);
    float* a_src2v = (float*)alloc((size_t)N * 4);
    float* a_dst2v = (float*)alloc((size_t)N * 4);
    int*   deg     = (int*)alloc((size_t)N * 4);
    int*   row_st  = (int*)alloc((size_t)(N + 1) * 4);
    int*   cursor  = (int*)alloc((size_t)N * 4);
    int*   csr_src = (int*)alloc((size_t)ET * 4);

    hipMemsetAsync(deg, 0, (size_t)N * 4, stream);

    const int nblk_x   = (N * 64) / 256;       // 12500
    const int nblk_cnt = (ET + 255) / 256;     // 3321
    prep_kernel<<<nblk_x + nblk_cnt + 2, 256, 0, stream>>>(
        x, W1, as1, ad1, ei, E, ET, xb, W1b, w_att, deg, nblk_x, nblk_cnt);
    gemm1_mfma_kernel<<<(N + 127) / 128, 256, 0, stream>>>(
        (const short*)xb, (const short*)W1b, h1, N);
    attdot_kernel<<<N / 4, 256, 0, stream>>>(x, w_att, a_src1, a_dst1);
    scan_kernel<<<1, 1024, 0, stream>>>(deg, row_st, cursor, N);
    scatter_kernel<<<(ET + 255) / 256, 256, 0, stream>>>(ei, E, ET, cursor, csr_src);
    agg1_layer2_kernel<<<N, 256, 0, stream>>>(
        row_st, csr_src, (const uint2*)h1, a_src1, a_dst1,
        b1, W2, as2, ad2, h2, a_src2v, a_dst2v);
    aggregate2_csr_kernel<<<(N + 3) / 4, 256, 0, stream>>>(
        row_st, csr_src, h2, a_src2v, a_dst2v, b2p, (float*)d_out, N);
}

// Round 7
// 353.971 us; speedup vs baseline: 3.7649x; 1.2753x over previous
//
#include <hip/hip_runtime.h>
#include <hip/hip_bf16.h>
#include <stdint.h>

#define NEG_SLOPE 0.2f
#define EPSV 1e-16f

typedef __attribute__((ext_vector_type(8))) short bf16x8;   // 8 bf16 = 4 VGPRs
typedef __attribute__((ext_vector_type(4))) float f32x4;

static __device__ __forceinline__ float b2f(unsigned short u) {
    union { float f; uint32_t i; } v; v.i = ((uint32_t)u) << 16; return v.f;
}
static __device__ __forceinline__ unsigned short f2b(float f) {
    union { float f; uint32_t i; } v; v.f = f;
    uint32_t x = v.i;
    return (unsigned short)((x + 0x7FFFu + ((x >> 16) & 1u)) >> 16);
}
static __device__ __forceinline__ uint32_t f2b_pk(float a, float b) {
    return (uint32_t)f2b(a) | ((uint32_t)f2b(b) << 16);
}

// edges 0..E-1 from edge_index, edges E..ET-1 are self loops
static __device__ __forceinline__ void edge_sd(const int* __restrict__ ei,
                                               int e, int E, int& s, int& d) {
    if (e < E) { s = ei[e]; d = ei[E + e]; }
    else       { s = e - E; d = s; }
}

static __device__ __forceinline__ float edge_exp(float as, float ad) {
    float a = as + ad;
    a = a > 0.f ? a : NEG_SLOPE * a;
    return __expf(a);   // no max-subtraction: softmax shift-invariant, |a| is O(10)
}

// ---------------------------------------------------------------------------
// prep: (a) x -> bf16; (b) degree count; (c) W1 -> bf16; (d) w_att
// ---------------------------------------------------------------------------
__global__ __launch_bounds__(256) void prep_kernel(
    const float* __restrict__ x, const float* __restrict__ W1,
    const float* __restrict__ att_src1, const float* __restrict__ att_dst1,
    const int* __restrict__ ei, int E, int ET,
    uint32_t* __restrict__ xb, uint32_t* __restrict__ W1b,
    float* __restrict__ w_att, int* __restrict__ deg,
    int nblk_x, int nblk_cnt)
{
    int b = blockIdx.x, t = threadIdx.x;
    if (b < nblk_x) {
        int i = b * 256 + t;
        float2 v = ((const float2*)x)[i];
        xb[i] = f2b_pk(v.x, v.y);
    } else if (b < nblk_x + nblk_cnt) {
        int e = (b - nblk_x) * 256 + t;
        if (e < ET) {
            int s, d; edge_sd(ei, e, E, s, d);
            (void)s;
            atomicAdd(&deg[d], 1);
        }
    } else if (b == nblk_x + nblk_cnt) {
        for (int j = t; j < 16384; j += 256) {   // 256*128/2 packed pairs
            float2 v = ((const float2*)W1)[j];
            W1b[j] = f2b_pk(v.x, v.y);
        }
    } else {
        for (int idx = t; idx < 1024; idx += 256) {
            int vec = idx >> 7, k = idx & 127;
            int h = vec >> 1;
            const float* att = (vec & 1) ? att_dst1 : att_src1;
            float s = 0.f;
            for (int c = 0; c < 64; ++c)
                s += att[h * 64 + c] * W1[(size_t)(h * 64 + c) * 128 + k];
            w_att[idx] = s;
        }
    }
}

// ---------------------------------------------------------------------------
// a_src1[n,h] = x[n,:] . w_att[2h];  a_dst1[n,h] = x[n,:] . w_att[2h+1]
// ---------------------------------------------------------------------------
__global__ __launch_bounds__(256) void attdot_kernel(
    const float* __restrict__ x, const float* __restrict__ w_att,
    float* __restrict__ a_src1, float* __restrict__ a_dst1)
{
    int w = threadIdx.x >> 6, lane = threadIdx.x & 63;
    int n = blockIdx.x * 4 + w;
    float x0 = x[(size_t)n * 128 + lane];
    float x1 = x[(size_t)n * 128 + 64 + lane];
    float p[8];
    #pragma unroll
    for (int v = 0; v < 8; ++v)
        p[v] = x0 * w_att[v * 128 + lane] + x1 * w_att[v * 128 + 64 + lane];
    #pragma unroll
    for (int off = 32; off; off >>= 1) {
        #pragma unroll
        for (int v = 0; v < 8; ++v) p[v] += __shfl_xor(p[v], off);
    }
    if (lane == 0) {
        #pragma unroll
        for (int h = 0; h < 4; ++h) {
            a_src1[(size_t)n * 4 + h] = p[2 * h];
            a_dst1[(size_t)n * 4 + h] = p[2 * h + 1];
        }
    }
}

// ---------------------------------------------------------------------------
// h1 = xb @ W1b^T via MFMA bf16. Wave tile: 32 nodes x 256 channels, K=128.
// ---------------------------------------------------------------------------
__global__ __launch_bounds__(256) void gemm1_mfma_kernel(
    const short* __restrict__ xb, const short* __restrict__ W1b,
    unsigned short* __restrict__ h1, int N)
{
    const int t = threadIdx.x;
    const int wv = t >> 6, lane = t & 63;
    const int l15 = lane & 15, quad = lane >> 4;
    const int m0 = blockIdx.x * 128 + wv * 32;

    bf16x8 A[2][4];
    #pragma unroll
    for (int ms = 0; ms < 2; ++ms) {
        int m = m0 + ms * 16 + l15;
        int mr = m < N ? m : N - 1;
        const short* ap = xb + (size_t)mr * 128 + quad * 8;
        #pragma unroll
        for (int kk = 0; kk < 4; ++kk)
            A[ms][kk] = *(const bf16x8*)(ap + kk * 32);
    }

    f32x4 acc[2][16];
    #pragma unroll
    for (int ms = 0; ms < 2; ++ms)
        #pragma unroll
        for (int ct = 0; ct < 16; ++ct)
            acc[ms][ct] = (f32x4){0.f, 0.f, 0.f, 0.f};

    #pragma unroll
    for (int kk = 0; kk < 4; ++kk) {
        bf16x8 B[16];
        const short* bp = W1b + (size_t)l15 * 128 + kk * 32 + quad * 8;
        #pragma unroll
        for (int ct = 0; ct < 16; ++ct)
            B[ct] = *(const bf16x8*)(bp + (size_t)ct * 16 * 128);
        #pragma unroll
        for (int ct = 0; ct < 16; ++ct) {
            acc[0][ct] = __builtin_amdgcn_mfma_f32_16x16x32_bf16(A[0][kk], B[ct], acc[0][ct], 0, 0, 0);
            acc[1][ct] = __builtin_amdgcn_mfma_f32_16x16x32_bf16(A[1][kk], B[ct], acc[1][ct], 0, 0, 0);
        }
    }

    #pragma unroll
    for (int ms = 0; ms < 2; ++ms) {
        #pragma unroll
        for (int r = 0; r < 4; ++r) {
            int m = m0 + ms * 16 + quad * 4 + r;
            if (m < N) {
                unsigned short* hp = h1 + (size_t)m * 256 + l15;
                #pragma unroll
                for (int ct = 0; ct < 16; ++ct)
                    hp[ct * 16] = f2b(acc[ms][ct][r]);
            }
        }
    }
}

// ---------------- 3-phase parallel CSR scan (was 110us single-block) --------
// Phase 1: block b sums deg[b*1024 .. b*1024+1023] -> blocksum[b]
__global__ __launch_bounds__(256) void scan1_kernel(
    const int* __restrict__ deg, int* __restrict__ blocksum, int N)
{
    __shared__ int ws_[4];
    int t = threadIdx.x;
    int base = blockIdx.x * 1024 + t * 4;
    int s = 0;
    if (base + 3 < N) {
        int4 v = *(const int4*)(deg + base);
        s = v.x + v.y + v.z + v.w;
    } else {
        for (int i = base; i < N && i < base + 4; ++i) s += deg[i];
    }
    #pragma unroll
    for (int off = 32; off; off >>= 1) s += __shfl_xor(s, off);
    int w = t >> 6;
    if ((t & 63) == 0) ws_[w] = s;
    __syncthreads();
    if (t == 0) blocksum[blockIdx.x] = ws_[0] + ws_[1] + ws_[2] + ws_[3];
}

// Phase 2: one wave exclusive-scans blocksum[0..nblk) (nblk <= 64)
__global__ __launch_bounds__(64) void scan2_kernel(
    int* __restrict__ blocksum, int* __restrict__ blockoff,
    int* __restrict__ row_start, int N, int nblk)
{
    int t = threadIdx.x;
    int orig = (t < nblk) ? blocksum[t] : 0;
    int v = orig;
    #pragma unroll
    for (int off = 1; off < 64; off <<= 1) {
        int u = __shfl_up(v, off);
        if (t >= off) v += u;
    }
    if (t < nblk) blockoff[t] = v - orig;
    if (t == nblk - 1) row_start[N] = v;   // total edge count
}

// Phase 3: re-read degrees, block-local exclusive scan, write row_start/cursor
__global__ __launch_bounds__(256) void scan3_kernel(
    const int* __restrict__ deg, const int* __restrict__ blockoff,
    int* __restrict__ row_start, int* __restrict__ cursor, int N)
{
    __shared__ int sums[256];
    int t = threadIdx.x;
    int base = blockIdx.x * 1024 + t * 4;
    int v0 = 0, v1 = 0, v2 = 0, v3 = 0;
    if (base + 3 < N) {
        int4 v = *(const int4*)(deg + base);
        v0 = v.x; v1 = v.y; v2 = v.z; v3 = v.w;
    } else {
        if (base     < N) v0 = deg[base];
        if (base + 1 < N) v1 = deg[base + 1];
        if (base + 2 < N) v2 = deg[base + 2];
        if (base + 3 < N) v3 = deg[base + 3];
    }
    int s = v0 + v1 + v2 + v3;
    sums[t] = s;
    __syncthreads();
    #pragma unroll
    for (int off = 1; off < 256; off <<= 1) {
        int u = (t >= off) ? sums[t - off] : 0;
        __syncthreads();
        sums[t] += u;
        __syncthreads();
    }
    int r = sums[t] - s + blockoff[blockIdx.x];
    if (base     < N) { row_start[base]     = r; cursor[base]     = r; r += v0; }
    if (base + 1 < N) { row_start[base + 1] = r; cursor[base + 1] = r; r += v1; }
    if (base + 2 < N) { row_start[base + 2] = r; cursor[base + 2] = r; r += v2; }
    if (base + 3 < N) { row_start[base + 3] = r; cursor[base + 3] = r; }
}

__global__ void scatter_kernel(const int* __restrict__ ei, int E, int ET,
                               int* __restrict__ cursor, int* __restrict__ csr_src)
{
    int e = blockIdx.x * blockDim.x + threadIdx.x;
    if (e >= ET) return;
    int s, d; edge_sd(ei, e, E, s, d);
    int p = atomicAdd(&cursor[d], 1);
    csr_src[p] = s;
}

// ---------------------------------------------------------------------------
// Fused layer-1 aggregate + layer-2 GEMM.
// ---------------------------------------------------------------------------
__global__ __launch_bounds__(256) void agg1_layer2_kernel(
    const int* __restrict__ row_start, const int* __restrict__ csr_src,
    const uint2* __restrict__ h1v,
    const float* __restrict__ a_src1, const float* __restrict__ a_dst1,
    const float* __restrict__ b1, const float* __restrict__ W2,
    const float* __restrict__ as2, const float* __restrict__ ad2,
    float* __restrict__ h2, float* __restrict__ a_src2, float* __restrict__ a_dst2)
{
    __shared__ float sacc[4][256];
    __shared__ float sden[4][4];
    __shared__ float red0[4], red1[4];

    const int n = blockIdx.x, t = threadIdx.x;
    const int w = t >> 6, lane = t & 63;
    const int h = lane >> 4;
    const int lo = row_start[n], hi = row_start[n + 1];
    const float adh = a_dst1[(size_t)n * 4 + h];

    float a0 = 0.f, a1 = 0.f, a2 = 0.f, a3 = 0.f, den = 0.f;
    int i = lo + w;
    int sn = (i < hi) ? csr_src[i] : 0;
    for (; i < hi; i += 4) {
        int s = sn;
        int inext = i + 4;
        if (inext < hi) sn = csr_src[inext];
        float ex = edge_exp(a_src1[(size_t)s * 4 + h], adh);
        uint2 r = h1v[(size_t)s * 64 + lane];
        a0 += ex * b2f((unsigned short)(r.x & 0xFFFF));
        a1 += ex * b2f((unsigned short)(r.x >> 16));
        a2 += ex * b2f((unsigned short)(r.y & 0xFFFF));
        a3 += ex * b2f((unsigned short)(r.y >> 16));
        den += ex;
    }
    float* sa = &sacc[w][lane * 4];
    sa[0] = a0; sa[1] = a1; sa[2] = a2; sa[3] = a3;
    if ((lane & 15) == 0) sden[w][h] = den;
    __syncthreads();

    const int c = t, hh = c >> 6;
    float acc = sacc[0][c] + sacc[1][c] + sacc[2][c] + sacc[3][c];
    float dn  = sden[0][hh] + sden[1][hh] + sden[2][hh] + sden[3][hh];
    float v = acc / (dn + EPSV) + b1[c];
    v = v > 0.f ? v : 0.f;

    float p0 = v * W2[c];
    float p1 = v * W2[256 + c];
    #pragma unroll
    for (int off = 32; off; off >>= 1) {
        p0 += __shfl_xor(p0, off);
        p1 += __shfl_xor(p1, off);
    }
    if (lane == 0) { red0[w] = p0; red1[w] = p1; }
    __syncthreads();
    if (t == 0) {
        float h0  = red0[0] + red0[1] + red0[2] + red0[3];
        float h1s = red1[0] + red1[1] + red1[2] + red1[3];
        h2[(size_t)n * 2]     = h0;
        h2[(size_t)n * 2 + 1] = h1s;
        a_src2[n] = h0 * as2[0] + h1s * as2[1];
        a_dst2[n] = h0 * ad2[0] + h1s * ad2[1];
    }
}

// ---------------- Layer-2 aggregate: wave per dst node, fused bias ----------
__global__ __launch_bounds__(256) void aggregate2_csr_kernel(
    const int* __restrict__ row_start, const int* __restrict__ csr_src,
    const float* __restrict__ h2,
    const float* __restrict__ a_src2, const float* __restrict__ a_dst2,
    const float* __restrict__ b2, float* __restrict__ out, int N)
{
    int w = threadIdx.x >> 6, lane = threadIdx.x & 63;
    int n = blockIdx.x * 4 + w;
    if (n >= N) return;
    int lo = row_start[n], hi = row_start[n + 1];
    float ad = a_dst2[n];
    float den = 0.f, num0 = 0.f, num1 = 0.f;
    for (int i = lo + lane; i < hi; i += 64) {
        int s = csr_src[i];
        float ex = edge_exp(a_src2[s], ad);
        float2 hh = ((const float2*)h2)[s];
        den  += ex;
        num0 += ex * hh.x;
        num1 += ex * hh.y;
    }
    #pragma unroll
    for (int off = 32; off; off >>= 1) {
        den  += __shfl_xor(den, off);
        num0 += __shfl_xor(num0, off);
        num1 += __shfl_xor(num1, off);
    }
    if (lane == 0) {
        float inv = 1.f / (den + EPSV);
        out[(size_t)n * 2]     = num0 * inv + b2[0];
        out[(size_t)n * 2 + 1] = num1 * inv + b2[1];
    }
}

// ---------------------------------------------------------------------------
extern "C" void kernel_launch(void* const* d_in, const int* in_sizes, int n_in,
                              void* d_out, int out_size, void* d_ws, size_t ws_size,
                              hipStream_t stream)
{
    const float* x   = (const float*)d_in[0];
    const int*   ei  = (const int*)d_in[1];
    const float* W1  = (const float*)d_in[2];
    const float* as1 = (const float*)d_in[3];
    const float* ad1 = (const float*)d_in[4];
    const float* b1  = (const float*)d_in[5];
    const float* W2  = (const float*)d_in[6];
    const float* as2 = (const float*)d_in[7];
    const float* ad2 = (const float*)d_in[8];
    const float* b2p = (const float*)d_in[9];

    const int N  = in_sizes[0] / 128;   // 50000
    const int E  = in_sizes[1] / 2;     // 800000
    const int ET = E + N;               // + self loops

    // Workspace ~45 MB (overflow at 123 MB corrupted pristine inputs in R1).
    char* ws = (char*)d_ws;
    size_t off = 0;
    auto alloc = [&](size_t bytes) -> char* {
        char* p = ws + off;
        off = (off + bytes + 255) & ~(size_t)255;
        return p;
    };
    uint32_t* xb   = (uint32_t*)alloc((size_t)N * 64 * 4);        // x as bf16 pairs
    uint32_t* W1b  = (uint32_t*)alloc((size_t)16384 * 4);         // W1 as bf16 pairs
    float* w_att   = (float*)alloc((size_t)1024 * 4);             // 8 x 128
    unsigned short* h1 = (unsigned short*)alloc((size_t)N * 256 * 2);
    float* a_src1  = (float*)alloc((size_t)N * 4 * 4);
    float* a_dst1  = (float*)alloc((size_t)N * 4 * 4);
    float* h2      = (float*)alloc((size_t)N * 2 * 4);
    float* a_src2v = (float*)alloc((size_t)N * 4);
    float* a_dst2v = (float*)alloc((size_t)N * 4);
    int*   deg     = (int*)alloc((size_t)N * 4);
    int*   row_st  = (int*)alloc((size_t)(N + 1) * 4);
    int*   cursor  = (int*)alloc((size_t)N * 4);
    int*   csr_src = (int*)alloc((size_t)ET * 4);
    const int nblk_scan = (N + 1023) / 1024;   // 49 (must stay <= 64 for scan2)
    int*   blocksum = (int*)alloc((size_t)nblk_scan * 4);
    int*   blockoff = (int*)alloc((size_t)nblk_scan * 4);

    hipMemsetAsync(deg, 0, (size_t)N * 4, stream);

    const int nblk_x   = (N * 64) / 256;       // 12500
    const int nblk_cnt = (ET + 255) / 256;     // 3321
    prep_kernel<<<nblk_x + nblk_cnt + 2, 256, 0, stream>>>(
        x, W1, as1, ad1, ei, E, ET, xb, W1b, w_att, deg, nblk_x, nblk_cnt);
    gemm1_mfma_kernel<<<(N + 127) / 128, 256, 0, stream>>>(
        (const short*)xb, (const short*)W1b, h1, N);
    attdot_kernel<<<N / 4, 256, 0, stream>>>(x, w_att, a_src1, a_dst1);
    scan1_kernel<<<nblk_scan, 256, 0, stream>>>(deg, blocksum, N);
    scan2_kernel<<<1, 64, 0, stream>>>(blocksum, blockoff, row_st, N, nblk_scan);
    scan3_kernel<<<nblk_scan, 256, 0, stream>>>(deg, blockoff, row_st, cursor, N);
    scatter_kernel<<<(ET + 255) / 256, 256, 0, stream>>>(ei, E, ET, cursor, csr_src);
    agg1_layer2_kernel<<<N, 256, 0, stream>>>(
        row_st, csr_src, (const uint2*)h1, a_src1, a_dst1,
        b1, W2, as2, ad2, h2, a_src2v, a_dst2v);
    aggregate2_csr_kernel<<<(N + 3) / 4, 256, 0, stream>>>(
        row_st, csr_src, h2, a_src2v, a_dst2v, b2p, (float*)d_out, N);
}